// Round 8
// baseline (439.547 us; speedup 1.0000x reference)
//
#include <hip/hip_runtime.h>

#define B_ 8
#define C_ 64
#define T_ 256
#define F_ 256
#define H_ 128
#define TF_ (T_*F_)

typedef _Float16 half_t;
typedef _Float16 half8 __attribute__((ext_vector_type(8)));
typedef _Float16 half4v __attribute__((ext_vector_type(4)));
typedef float float4v __attribute__((ext_vector_type(4)));

#if __has_builtin(__builtin_amdgcn_exp2f)
#define EXP2F(x) __builtin_amdgcn_exp2f(x)
#else
static __device__ inline float EXP2F(float x) { float r; asm("v_exp_f32 %0, %1" : "=v"(r) : "v"(x)); return r; }
#endif
#if __has_builtin(__builtin_amdgcn_rcpf)
#define RCPF(x) __builtin_amdgcn_rcpf(x)
#else
static __device__ inline float RCPF(float x) { float r; asm("v_rcp_f32 %0, %1" : "=v"(r) : "v"(x)); return r; }
#endif

// Barrier draining only LDS (lgkmcnt); global-load vmcnt stays in flight.
#define LDS_BARRIER() asm volatile("s_waitcnt lgkmcnt(0)\n\ts_barrier" ::: "memory")

#define NEG_L2E  (-1.4426950408889634f)
#define NEG_2L2E (-2.8853900817779268f)

// ---------------- Kernel 1: x [B,C,T,F] fp32 -> xt [B, T*F, C] fp16 ----------------
__global__ __launch_bounds__(256) void k_transpose(const float* __restrict__ x,
                                                   half_t* __restrict__ xt) {
    __shared__ float lds[64 * 68];      // stride 68: b128-readable, 4-way conflict max
    int blk = blockIdx.x;
    int b   = blk >> 10;            // /1024
    int tf0 = (blk & 1023) << 6;    // *64
    int tid = threadIdx.x;
    int s = tid & 15;               // tf sub-tile (x4)
    int q = tid >> 4;               // 0..15 c base
    const float* xp = x + (size_t)(b * C_) * TF_ + tf0 + s * 4;
#pragma unroll
    for (int i = 0; i < 4; ++i) {
        int c = q + i * 16;
        float4v v = *(const float4v*)(xp + (size_t)c * TF_);
#pragma unroll
        for (int j = 0; j < 4; ++j) lds[(s * 4 + j) * 68 + c] = v[j];
    }
    __syncthreads();
    int row = tid >> 2;             // 0..63 (tf local)
    int c0  = (tid & 3) << 4;       // 0,16,32,48
    half8 o0, o1;
#pragma unroll
    for (int kq = 0; kq < 4; ++kq) {
        float4v v = *(const float4v*)&lds[row * 68 + c0 + kq * 4];
#pragma unroll
        for (int j = 0; j < 4; ++j) {
            if (kq < 2) o0[kq * 4 + j] = (half_t)v[j];
            else        o1[(kq - 2) * 4 + j] = (half_t)v[j];
        }
    }
    half_t* op = xt + ((size_t)b * TF_ + tf0 + row) * C_ + c0;
    *(half8*)op       = o0;
    *(half8*)(op + 8) = o1;
}

// ---------------- Kernel 2: fused dual GRU, MFMA 16x16x32 f16, M=16/block ----------------
__device__ inline half8 load_w8s(const float* __restrict__ p, float s) {
    half8 r;
#pragma unroll
    for (int k = 0; k < 8; ++k) r[k] = (half_t)(p[k] * s);
    return r;
}

#define MFMA(a, b, c) __builtin_amdgcn_mfma_f32_16x16x32_f16((a), (b), (c), 0, 0, 0)

// 256 blocks (128 time + 128 freq), 512 thr = 8 waves; block owns M=16 sequences.
// Wave w owns hidden units [16w,16w+16).
// OPERAND-SWAPPED vs earlier rounds: A = weights (rows = js), B = h/x (cols =
// seqs). Same per-lane register contents; D[m=j][n=seq], so a lane's 4 acc regs
// are 4 CONSECUTIVE js of one seq -> LDS h-write is one ds_write_b64 and the
// epilogue store is dwordx4. Biases are per-reg float4.
// x-part accumulators ping-pong between two register sets so the refill (which
// has no h dependency) issues right after the h-MFMAs and hides under the
// nonlinearity. n-gate h-product stays entirely inside the r-multiplication.
__global__ __launch_bounds__(512, 2) void k_gru(
    const half_t* __restrict__ xt,
    const float* __restrict__ Wih_t, const float* __restrict__ Whh_t,
    const float* __restrict__ bih_t, const float* __restrict__ bhh_t,
    const float* __restrict__ Wih_f, const float* __restrict__ Whh_f,
    const float* __restrict__ bih_f, const float* __restrict__ bhh_f,
    float* __restrict__ h_t_out, float* __restrict__ h_f_out) {
    __shared__ half_t hbuf0[16 * 136];
    __shared__ half_t hbuf1[16 * 136];

    int tid  = threadIdx.x;
    int w    = tid >> 6;
    int lane = tid & 63;
    int nidx = lane & 15;           // seq index (B-operand n / D n)
    int quad = lane >> 4;
    int ko   = quad * 8;            // K offset within a 32-chunk

    int bi  = blockIdx.x;
    bool isf = bi >= 128;
    int lbi = bi & 127;
    int b   = lbi >> 4;
    int g16 = (lbi & 15) << 4;      // f0 (time) or t0 (freq)

    const float* Wih = isf ? Wih_f : Wih_t;
    const float* Whh = isf ? Whh_f : Whh_t;
    const float* bih = isf ? bih_f : bih_t;
    const float* bhh = isf ? bhh_f : bhh_t;
    float* hout      = isf ? h_f_out : h_t_out;

    size_t Sm = isf ? (size_t)(F_ * C_) : (size_t)C_;   // stride between sequences
    size_t Ss = isf ? (size_t)C_ : (size_t)(F_ * C_);   // stride per recurrence step
    size_t abase = (size_t)b * TF_ * C_ + (size_t)g16 * Sm;

    // ---- weight A-fragments in registers (loaded once, pre-scaled) ----
    int gr = w * 16 + nidx;     // this lane's W row within A-frags
    int gz = gr + 128;
    int gn = gr + 256;

    half8 wir0 = load_w8s(Wih + gr * 64 + ko,      NEG_L2E);
    half8 wir1 = load_w8s(Wih + gr * 64 + 32 + ko, NEG_L2E);
    half8 wiz0 = load_w8s(Wih + gz * 64 + ko,      NEG_L2E);
    half8 wiz1 = load_w8s(Wih + gz * 64 + 32 + ko, NEG_L2E);
    half8 win0 = load_w8s(Wih + gn * 64 + ko,      NEG_2L2E);
    half8 win1 = load_w8s(Wih + gn * 64 + 32 + ko, NEG_2L2E);
    half8 whr[4], whz[4], whn[4];
#pragma unroll
    for (int kt = 0; kt < 4; ++kt) {
        whr[kt] = load_w8s(Whh + gr * 128 + kt * 32 + ko, NEG_L2E);
        whz[kt] = load_w8s(Whh + gz * 128 + kt * 32 + ko, NEG_L2E);
        whn[kt] = load_w8s(Whh + gn * 128 + kt * 32 + ko, NEG_2L2E);
    }

    // ---- per-reg biases (D row j = w*16 + quad*4 + reg) ----
    int grb = w * 16 + quad * 4;
    float4v brv  = (*(const float4v*)(bih + grb)       + *(const float4v*)(bhh + grb))       * NEG_L2E;
    float4v bzv  = (*(const float4v*)(bih + grb + 128) + *(const float4v*)(bhh + grb + 128)) * NEG_L2E;
    float4v binv = (*(const float4v*)(bih + grb + 256)) * NEG_2L2E;
    float4v bhnv = (*(const float4v*)(bhh + grb + 256)) * NEG_2L2E;

    for (int idx = tid; idx < 16 * 136; idx += 512) hbuf0[idx] = (half_t)0.f;
    float h_old[4] = {0.f, 0.f, 0.f, 0.f};

    const half_t* ap = xt + abase + (size_t)nidx * Sm + ko;
    half8 xA0 = *(const half8*)ap;          // x_0
    half8 xA1 = *(const half8*)(ap + 32);
    ap += Ss;
    half8 xB0 = *(const half8*)ap;          // x_1
    half8 xB1 = *(const half8*)(ap + 32);
    ap += Ss;

    // x-part accumulator set A for step 0 (from x_0)
    float4v xrA = MFMA(wir0, xA0, brv);  xrA = MFMA(wir1, xA1, xrA);
    float4v xzA = MFMA(wiz0, xA0, bzv);  xzA = MFMA(wiz1, xA1, xzA);
    float4v xnA = MFMA(win0, xA0, binv); xnA = MFMA(win1, xA1, xnA);
    float4v xrB, xzB, xnB;
    LDS_BARRIER();   // hbuf0 zeros visible

    const float4v zero4 = {0.f, 0.f, 0.f, 0.f};

    // XRC/XZC/XNC: consumed x-accumulators; XRF/XZF/XNF: refilled for next step;
    // XC0/XC1: x regs feeding the refill; XP0/XP1: prefetch target for t+2.
#define GRU_STEP(RBUF, WBUF, XRC, XZC, XNC, XRF, XZF, XNF, XC0, XC1, XP0, XP1)  \
    {                                                                           \
        const half_t* hrow = (RBUF) + nidx * 136 + ko;                          \
        half8 ha0 = *(const half8*)(hrow);                                      \
        half8 ha1 = *(const half8*)(hrow + 32);                                 \
        half8 ha2 = *(const half8*)(hrow + 64);                                 \
        half8 ha3 = *(const half8*)(hrow + 96);                                 \
        XP0 = *(const half8*)ap;                                                \
        XP1 = *(const half8*)(ap + 32);                                         \
        ap += Ss;                                                               \
        float4v grv = MFMA(whr[0], ha0, XRC);  grv = MFMA(whr[1], ha1, grv);    \
        float4v rp  = MFMA(whr[2], ha2, zero4); rp = MFMA(whr[3], ha3, rp);     \
        float4v gzv = MFMA(whz[0], ha0, XZC);  gzv = MFMA(whz[1], ha1, gzv);    \
        float4v zp  = MFMA(whz[2], ha2, zero4); zp = MFMA(whz[3], ha3, zp);     \
        float4v na  = MFMA(whn[0], ha0, bhnv); na  = MFMA(whn[1], ha1, na);     \
        float4v nb  = MFMA(whn[2], ha2, zero4); nb = MFMA(whn[3], ha3, nb);     \
        /* refill next step's x-accumulators (independent: hides under nonlin) */\
        XRF = MFMA(wir0, XC0, brv);  XRF = MFMA(wir1, XC1, XRF);                \
        XZF = MFMA(wiz0, XC0, bzv);  XZF = MFMA(wiz1, XC1, XZF);                \
        XNF = MFMA(win0, XC0, binv); XNF = MFMA(win1, XC1, XNF);                \
        half4v hw;                                                              \
        _Pragma("unroll")                                                       \
        for (int rg = 0; rg < 4; ++rg) {                                        \
            float r  = RCPF(1.f + EXP2F(grv[rg] + rp[rg]));                     \
            float np = XNC[rg] + r * (na[rg] + nb[rg]);                         \
            float n  = 2.f * RCPF(1.f + EXP2F(np)) - 1.f;                       \
            float z  = RCPF(1.f + EXP2F(gzv[rg] + zp[rg]));                     \
            float h  = n + z * (h_old[rg] - n);                                 \
            h_old[rg] = h;                                                      \
            hw[rg] = (half_t)h;                                                 \
        }                                                                       \
        *(half4v*)((WBUF) + nidx * 136 + w * 16 + quad * 4) = hw;               \
        LDS_BARRIER();                                                          \
    }

    for (int it = 0; it < 128; ++it) {
        // even step: reads hbuf0 -> hbuf1; consumes set A; refills set B from xB (x_{t+1}); prefetch into xA
        GRU_STEP(hbuf0, hbuf1, xrA, xzA, xnA, xrB, xzB, xnB, xB0, xB1, xA0, xA1)
        // odd step: reads hbuf1 -> hbuf0; consumes set B; refills set A from xA; prefetch into xB
        // (tail prefetch/refill read slightly past xt: stays inside d_out, unused)
        GRU_STEP(hbuf1, hbuf0, xrB, xzB, xnB, xrA, xzA, xnA, xA0, xA1, xB0, xB1)
    }
#undef GRU_STEP

    int srow = (b << 8) + g16;
    float4v hv = {h_old[0], h_old[1], h_old[2], h_old[3]};
    *(float4v*)(hout + (size_t)(srow + nidx) * H_ + w * 16 + quad * 4) = hv;
}

// ---------------- Kernel 3: out[b,c,t,f] = bp[c] + sum_h Wp[c,h]*(h_t[b,t,h]+h_f[b,t,h]) ----------------
__global__ __launch_bounds__(256) void k_out(const float* __restrict__ h_t,
                                             const float* __restrict__ h_f,
                                             const float* __restrict__ Wp,
                                             const float* __restrict__ bp,
                                             float* __restrict__ out) {
    __shared__ float sv[128];
    __shared__ float part[4][64];
    __shared__ float orow[64];
    int blk = blockIdx.x;
    int b = blk >> 8;
    int i = blk & 255;              // t index
    int tid = threadIdx.x;
    size_t hoff = ((size_t)(b * 256 + i)) * 128;
    if (tid < 128) sv[tid] = h_t[hoff + tid] + h_f[hoff + tid];
    __syncthreads();
    int c = tid & 63;
    int q = tid >> 6;
    float p = 0.f;
    const float* wp = Wp + c * 128 + q * 32;
#pragma unroll
    for (int k = 0; k < 32; ++k) p += wp[k] * sv[q * 32 + k];
    part[q][c] = p;
    __syncthreads();
    if (tid < 64) orow[tid] = part[0][tid] + part[1][tid] + part[2][tid] + part[3][tid] + bp[tid];
    __syncthreads();
    // wave wv writes full contiguous rows out[b, c, i, 0:256] (1 KB each)
    int wv   = tid >> 6;
    int lane = tid & 63;
#pragma unroll
    for (int itr = 0; itr < 16; ++itr) {
        int cc = itr * 4 + wv;
        float v = orow[cc];
        float4v vv = {v, v, v, v};
        *(float4v*)(out + (((size_t)(b * 64 + cc)) * 256 + i) * 256 + lane * 4) = vv;
    }
}

extern "C" void kernel_launch(void* const* d_in, const int* in_sizes, int n_in,
                              void* d_out, int out_size, void* d_ws, size_t ws_size,
                              hipStream_t stream) {
    const float* x     = (const float*)d_in[0];
    const float* Wih_t = (const float*)d_in[1];
    const float* Whh_t = (const float*)d_in[2];
    const float* bih_t = (const float*)d_in[3];
    const float* bhh_t = (const float*)d_in[4];
    const float* Wih_f = (const float*)d_in[5];
    const float* Whh_f = (const float*)d_in[6];
    const float* bih_f = (const float*)d_in[7];
    const float* bhh_f = (const float*)d_in[8];
    const float* Wp    = (const float*)d_in[9];
    const float* bp    = (const float*)d_in[10];
    float* out = (float*)d_out;

    // xt (fp16, 64 MiB) lives in the first half of d_out (128 MiB): fully
    // consumed by k_gru before k_out overwrites d_out. h_t/h_f live in ws.
    half_t* xt     = (half_t*)d_out;
    float* h_t_out = (float*)((char*)d_ws);
    float* h_f_out = (float*)((char*)d_ws + (size_t)2048 * 128 * 4);

    k_transpose<<<8192, 256, 0, stream>>>(x, xt);
    k_gru<<<256, 512, 0, stream>>>(xt, Wih_t, Whh_t, bih_t, bhh_t,
                                   Wih_f, Whh_f, bih_f, bhh_f, h_t_out, h_f_out);
    k_out<<<2048, 256, 0, stream>>>(h_t_out, h_f_out, Wp, bp, out);
}